// Round 1
// 498.719 us; speedup vs baseline: 1.0491x; 1.0491x over previous
//
#include <hip/hip_runtime.h>

#define NN 131072
#define DD 512
#define CC 1000

// pair term tiling
#define CT 64
#define KCP 32
#define NTILE 16     // ceil(1000/64)
#define NPAIR 136    // NTILE*(NTILE+1)/2 upper-tri tile pairs
// sample term
#define SROWS 8
#define NSAMP (NN / SROWS)

typedef float f32x4 __attribute__((ext_vector_type(4)));
typedef float f32x2 __attribute__((ext_vector_type(2)));

// ws layout (floats):
//       0 : w          [CC*DD]   normalized classifier
//  512000 : sqw        [CC]      sum(w*w) per row
//  513000 : class_sum  [CC]
//  514000 : class_cnt  [CC]
//  515000 : pair_acc   [2]       {sum of 1/d2, mask count}

__device__ __forceinline__ float wave_reduce(float v) {
#pragma unroll
    for (int m = 32; m > 0; m >>= 1) v += __shfl_xor(v, m, 64);
    return v;
}

// --- normalize classifier rows: one wave per row ---
__global__ __launch_bounds__(64) void knorm(const float* __restrict__ cls,
                                            float* __restrict__ w,
                                            float* __restrict__ sqw) {
    int c = blockIdx.x;
    int lane = threadIdx.x;
    const float4* src = (const float4*)(cls + (size_t)c * DD) + lane * 2;
    float4 f0 = src[0], f1 = src[1];
    float s = f0.x * f0.x + f0.y * f0.y + f0.z * f0.z + f0.w * f0.w +
              f1.x * f1.x + f1.y * f1.y + f1.z * f1.z + f1.w * f1.w;
    s = wave_reduce(s);
    float inv = rsqrtf(s);
    float4 w0 = make_float4(f0.x * inv, f0.y * inv, f0.z * inv, f0.w * inv);
    float4 w1 = make_float4(f1.x * inv, f1.y * inv, f1.z * inv, f1.w * inv);
    float q = w0.x * w0.x + w0.y * w0.y + w0.z * w0.z + w0.w * w0.w +
              w1.x * w1.x + w1.y * w1.y + w1.z * w1.z + w1.w * w1.w;
    q = wave_reduce(q);
    float4* dst = (float4*)(w + (size_t)c * DD) + lane * 2;
    dst[0] = w0;
    dst[1] = w1;
    if (lane == 0) sqw[c] = q;
}

// --- fused kernel: blockIdx < NPAIR -> pair tiles (VALU/LDS bound),
//     rest -> sample rows (HBM streaming). Disjoint pipes overlap. ---
__global__ __launch_bounds__(256) void kmain(const float* __restrict__ feat,
                                             const int* __restrict__ target,
                                             const float* __restrict__ w,
                                             const float* __restrict__ sqw,
                                             float* __restrict__ class_sum,
                                             float* __restrict__ class_cnt,
                                             float* __restrict__ pair_acc,
                                             float* __restrict__ out_feat) {
    int t = threadIdx.x;

    if (blockIdx.x < NPAIR) {
        // ---------------- pair term: 64x64 tile, 4x4 per thread ----------------
        // Transposed LDS (As[k][i]) so fragments are float4-contiguous:
        // 2 ds_read_b128 feed 16 FMAs per k.
        __shared__ float As[KCP][CT + 4];   // stride 68 floats = 272B (16B aligned rows)
        __shared__ float Bs[KCP][CT + 4];
        __shared__ float rs[4], rc[4];

        // linear upper-tri tile index -> (bi, bj), bi <= bj
        int bi = 0, rem = blockIdx.x;
        while (rem >= NTILE - bi) { rem -= NTILE - bi; ++bi; }
        int bj = bi + rem;
        int i0 = bi * CT, j0 = bj * CT;

        int tx = t & 15, ty = t >> 4;   // 16x16 threads, each 4x4 outputs
        int lrow = t >> 2;              // 0..63 : row loaded by this thread
        int kc = (t & 3) * 8;           // 0,8,16,24 : k-chunk loaded

        float acc[4][4] = {{0.f, 0.f, 0.f, 0.f}};

        for (int k0 = 0; k0 < DD; k0 += KCP) {
            f32x4 a0 = {0.f, 0.f, 0.f, 0.f}, a1 = a0, b0 = a0, b1 = a0;
            int gi = i0 + lrow, gj = j0 + lrow;
            if (gi < CC) {
                const f32x4* p = (const f32x4*)(w + (size_t)gi * DD + k0 + kc);
                a0 = p[0]; a1 = p[1];
            }
            if (gj < CC) {
                const f32x4* p = (const f32x4*)(w + (size_t)gj * DD + k0 + kc);
                b0 = p[0]; b1 = p[1];
            }
            __syncthreads();   // previous iter's reads done before overwrite
            As[kc + 0][lrow] = a0.x; As[kc + 1][lrow] = a0.y;
            As[kc + 2][lrow] = a0.z; As[kc + 3][lrow] = a0.w;
            As[kc + 4][lrow] = a1.x; As[kc + 5][lrow] = a1.y;
            As[kc + 6][lrow] = a1.z; As[kc + 7][lrow] = a1.w;
            Bs[kc + 0][lrow] = b0.x; Bs[kc + 1][lrow] = b0.y;
            Bs[kc + 2][lrow] = b0.z; Bs[kc + 3][lrow] = b0.w;
            Bs[kc + 4][lrow] = b1.x; Bs[kc + 5][lrow] = b1.y;
            Bs[kc + 6][lrow] = b1.z; Bs[kc + 7][lrow] = b1.w;
            __syncthreads();
#pragma unroll
            for (int k = 0; k < KCP; ++k) {
                f32x4 av = *(const f32x4*)&As[k][4 * ty];
                f32x4 bv = *(const f32x4*)&Bs[k][4 * tx];
#pragma unroll
                for (int a = 0; a < 4; ++a)
#pragma unroll
                    for (int b = 0; b < 4; ++b)
                        acc[a][b] += av[a] * bv[b];
            }
        }

        float lsum = 0.f, lcnt = 0.f;
        int ib = i0 + 4 * ty, jb = j0 + 4 * tx;
#pragma unroll
        for (int a = 0; a < 4; ++a)
#pragma unroll
            for (int b = 0; b < 4; ++b) {
                int i = ib + a, j = jb + b;
                if (j > i && j < CC) {  // i < j < CC implies i < CC
                    float d2 = sqw[i] + sqw[j] - 2.f * acc[a][b];
                    if (d2 > 0.f) { lsum += 1.f / d2; lcnt += 1.f; }
                }
            }
        lsum = wave_reduce(lsum);
        lcnt = wave_reduce(lcnt);
        int wv = t >> 6;
        if ((t & 63) == 0) { rs[wv] = lsum; rc[wv] = lcnt; }
        __syncthreads();
        if (t == 0) {
            atomicAdd(pair_acc + 0, rs[0] + rs[1] + rs[2] + rs[3]);
            atomicAdd(pair_acc + 1, rc[0] + rc[1] + rc[2] + rc[3]);
        }
        return;
    }

    // ---------------- sample term: 8 rows/block, 4-deep ILP per thread ----------------
    // Each 128-thread group owns 4 rows (unrolled in registers): 4 independent
    // feat loads + 4 w loads + 8 stores in flight, shuffle trees interleaved.
    __shared__ float red[8][4][2];  // [32-lane group][row idx][ff,fw]
    long long n0 = (long long)(blockIdx.x - NPAIR) * SROWS;
    int col4 = t & 127;   // float4 column within a row
    int rhalf = t >> 7;   // 0: rows n0+0,2,4,6   1: rows n0+1,3,5,7

    const f32x4* f4 = (const f32x4*)feat;
    const f32x4* w4 = (const f32x4*)w;
    f32x2* o2 = (f32x2*)out_feat;

    int tg[4];
#pragma unroll
    for (int i = 0; i < 4; ++i) tg[i] = target[n0 + rhalf + 2 * i];

    size_t fi[4];
    f32x4 f[4];
#pragma unroll
    for (int i = 0; i < 4; ++i) {
        fi[i] = (size_t)(n0 + rhalf + 2 * i) * 128 + col4;
        f[i] = __builtin_nontemporal_load(f4 + fi[i]);  // streaming: don't pollute L2
    }

    f32x4 wv[4];
#pragma unroll
    for (int i = 0; i < 4; ++i) wv[i] = w4[(size_t)tg[i] * 128 + col4];

#pragma unroll
    for (int i = 0; i < 4; ++i) {  // passthrough copy (dest only 8B aligned)
        f32x2 lo = {f[i].x, f[i].y}, hi = {f[i].z, f[i].w};
        __builtin_nontemporal_store(lo, o2 + 2 * fi[i]);
        __builtin_nontemporal_store(hi, o2 + 2 * fi[i] + 1);
    }

    float ff[4], fw[4];
#pragma unroll
    for (int i = 0; i < 4; ++i) {
        ff[i] = f[i].x * f[i].x + f[i].y * f[i].y + f[i].z * f[i].z + f[i].w * f[i].w;
        fw[i] = f[i].x * wv[i].x + f[i].y * wv[i].y + f[i].z * wv[i].z + f[i].w * wv[i].w;
    }
    // reduce within 32-lane halves only (DPP, no cross-32 hop); LDS combines the rest
#pragma unroll
    for (int m = 16; m > 0; m >>= 1)
#pragma unroll
        for (int i = 0; i < 4; ++i) {
            ff[i] += __shfl_xor(ff[i], m, 64);
            fw[i] += __shfl_xor(fw[i], m, 64);
        }
    int p = t >> 5;
    if ((t & 31) == 0) {
#pragma unroll
        for (int i = 0; i < 4; ++i) { red[p][i][0] = ff[i]; red[p][i][1] = fw[i]; }
    }
    __syncthreads();
    if ((t & 127) < 4) {  // 8 finalizer threads/block, one row each
        int i = t & 127;
        int base = rhalf * 4;
        float sff = red[base][i][0] + red[base + 1][i][0] +
                    red[base + 2][i][0] + red[base + 3][i][0];
        float sfw = red[base][i][1] + red[base + 1][i][1] +
                    red[base + 2][i][1] + red[base + 3][i][1];
        int tgt = tg[i];
        float inv = rsqrtf(sff);
        float d2 = sff * inv * inv + sqw[tgt] - 2.f * inv * sfw;
        d2 = fmaxf(d2, 0.f);
        atomicAdd(class_sum + tgt, sqrtf(d2));
        atomicAdd(class_cnt + tgt, 1.f);
    }
}

// --- finalize both scalars ---
__global__ __launch_bounds__(256) void kfin(const float* __restrict__ class_sum,
                                            const float* __restrict__ class_cnt,
                                            const float* __restrict__ pair_acc,
                                            float* __restrict__ out) {
    float msum = 0.f, pcnt = 0.f;
    for (int c = threadIdx.x; c < CC; c += 256) {
        float cnt = class_cnt[c];
        if (cnt > 0.f) {
            msum += class_sum[c] / cnt;
            pcnt += 1.f;
        }
    }
    msum = wave_reduce(msum);
    pcnt = wave_reduce(pcnt);
    __shared__ float rs[4], rc[4];
    int wv = threadIdx.x >> 6;
    if ((threadIdx.x & 63) == 0) { rs[wv] = msum; rc[wv] = pcnt; }
    __syncthreads();
    if (threadIdx.x == 0) {
        float sm = rs[0] + rs[1] + rs[2] + rs[3];
        float sp = rc[0] + rc[1] + rc[2] + rc[3];
        out[0] = 1.0f * (sm / sp);                   // BETA * sample_wise
        out[1] = 1.0f * (pair_acc[0] / pair_acc[1]); // ALPHA * weight_wise
    }
}

extern "C" void kernel_launch(void* const* d_in, const int* in_sizes, int n_in,
                              void* d_out, int out_size, void* d_ws, size_t ws_size,
                              hipStream_t stream) {
    const float* feat = (const float*)d_in[0];
    const float* cls = (const float*)d_in[1];
    const int* target = (const int*)d_in[2];
    float* out = (float*)d_out;
    float* ws = (float*)d_ws;

    float* w = ws;
    float* sqw = ws + 512000;
    float* class_sum = ws + 513000;
    float* class_cnt = ws + 514000;
    float* pair_acc = ws + 515000;

    // zero accumulators (class_sum, class_cnt, pair_acc are contiguous)
    hipMemsetAsync(class_sum, 0, (2 * CC + 2) * sizeof(float), stream);

    knorm<<<CC, 64, 0, stream>>>(cls, w, sqw);
    kmain<<<NPAIR + NSAMP, 256, 0, stream>>>(feat, target, w, sqw,
                                             class_sum, class_cnt, pair_acc, out + 2);
    kfin<<<1, 256, 0, stream>>>(class_sum, class_cnt, pair_acc, out);
}

// Round 2
// 498.436 us; speedup vs baseline: 1.0497x; 1.0006x over previous
//
#include <hip/hip_runtime.h>

#define NN 131072
#define DD 512
#define CC 1000

// pair term tiling
#define CT 64
#define KCP 32
#define NTILE 16     // ceil(1000/64)
#define NPAIR 136    // NTILE*(NTILE+1)/2 upper-tri tile pairs
// sample term: 4 waves/block, 2 rows/wave
#define SROWS 8
#define NSAMP (NN / SROWS)

typedef float f32x4 __attribute__((ext_vector_type(4)));
typedef float f32x2 __attribute__((ext_vector_type(2)));

// ws layout (floats):
//       0 : w          [CC*DD]   normalized classifier
//  512000 : sqw        [CC]      sum(w*w) per row
//  513000 : class_sum  [CC]
//  514000 : class_cnt  [CC]
//  515000 : pair_acc   [2]       {sum of 1/d2, mask count}

__device__ __forceinline__ float wave_reduce(float v) {
#pragma unroll
    for (int m = 32; m > 0; m >>= 1) v += __shfl_xor(v, m, 64);
    return v;
}

__device__ __forceinline__ float dot4(f32x4 a, f32x4 b) {
    return a.x * b.x + a.y * b.y + a.z * b.z + a.w * b.w;
}

// --- normalize classifier rows: one wave per row ---
__global__ __launch_bounds__(64) void knorm(const float* __restrict__ cls,
                                            float* __restrict__ w,
                                            float* __restrict__ sqw) {
    int c = blockIdx.x;
    int lane = threadIdx.x;
    const float4* src = (const float4*)(cls + (size_t)c * DD) + lane * 2;
    float4 f0 = src[0], f1 = src[1];
    float s = f0.x * f0.x + f0.y * f0.y + f0.z * f0.z + f0.w * f0.w +
              f1.x * f1.x + f1.y * f1.y + f1.z * f1.z + f1.w * f1.w;
    s = wave_reduce(s);
    float inv = rsqrtf(s);
    float4 w0 = make_float4(f0.x * inv, f0.y * inv, f0.z * inv, f0.w * inv);
    float4 w1 = make_float4(f1.x * inv, f1.y * inv, f1.z * inv, f1.w * inv);
    float q = w0.x * w0.x + w0.y * w0.y + w0.z * w0.z + w0.w * w0.w +
              w1.x * w1.x + w1.y * w1.y + w1.z * w1.z + w1.w * w1.w;
    q = wave_reduce(q);
    float4* dst = (float4*)(w + (size_t)c * DD) + lane * 2;
    dst[0] = w0;
    dst[1] = w1;
    if (lane == 0) sqw[c] = q;
}

// --- store one row's 512 floats to out_feat (dest base is only 8B-aligned).
// Lane l holds v0 = f[4l..4l+3], v1 = f[256+4l..256+4l+3].
// Aligned float4 stores cover e=4m+2..4m+5 (m=0..126) via a lane-rotate shuffle;
// head (e=0,1) and tail (e=510,511) are 8B stores.
__device__ __forceinline__ void store_row(float* __restrict__ orow, int lane,
                                          f32x4 v0, f32x4 v1) {
    int nl = (lane + 1) & 63;
    float s0x = __shfl(v0.x, nl, 64), s0y = __shfl(v0.y, nl, 64);
    float s1x = __shfl(v1.x, nl, 64), s1y = __shfl(v1.y, nl, 64);
    bool last = (lane == 63);
    f32x4 st1 = {v0.z, v0.w, last ? s1x : s0x, last ? s1y : s0y};
    __builtin_nontemporal_store(st1, (f32x4*)(orow + 2 + 4 * lane));
    if (!last) {
        f32x4 st2 = {v1.z, v1.w, s1x, s1y};
        __builtin_nontemporal_store(st2, (f32x4*)(orow + 258 + 4 * lane));
    } else {
        f32x2 tl = {v1.z, v1.w};
        __builtin_nontemporal_store(tl, (f32x2*)(orow + 510));
    }
    if (lane == 0) {
        f32x2 hd = {v0.x, v0.y};
        __builtin_nontemporal_store(hd, (f32x2*)(orow + 0));
    }
}

// --- fused kernel: blockIdx < NPAIR -> pair tiles (VALU/LDS bound),
//     rest -> sample rows (HBM streaming, no LDS/barriers). ---
__global__ __launch_bounds__(256) void kmain(const float* __restrict__ feat,
                                             const int* __restrict__ target,
                                             const float* __restrict__ w,
                                             const float* __restrict__ sqw,
                                             float* __restrict__ class_sum,
                                             float* __restrict__ class_cnt,
                                             float* __restrict__ pair_acc,
                                             float* __restrict__ out_feat) {
    int t = threadIdx.x;

    if (blockIdx.x < NPAIR) {
        // ---------------- pair term: 64x64 tile, 4x4 per thread ----------------
        __shared__ float As[KCP][CT + 4];
        __shared__ float Bs[KCP][CT + 4];
        __shared__ float rs[4], rc[4];

        int bi = 0, rem = blockIdx.x;
        while (rem >= NTILE - bi) { rem -= NTILE - bi; ++bi; }
        int bj = bi + rem;
        int i0 = bi * CT, j0 = bj * CT;

        int tx = t & 15, ty = t >> 4;
        int lrow = t >> 2;
        int kc = (t & 3) * 8;

        float acc[4][4] = {{0.f, 0.f, 0.f, 0.f}};

        for (int k0 = 0; k0 < DD; k0 += KCP) {
            f32x4 a0 = {0.f, 0.f, 0.f, 0.f}, a1 = a0, b0 = a0, b1 = a0;
            int gi = i0 + lrow, gj = j0 + lrow;
            if (gi < CC) {
                const f32x4* p = (const f32x4*)(w + (size_t)gi * DD + k0 + kc);
                a0 = p[0]; a1 = p[1];
            }
            if (gj < CC) {
                const f32x4* p = (const f32x4*)(w + (size_t)gj * DD + k0 + kc);
                b0 = p[0]; b1 = p[1];
            }
            __syncthreads();
            As[kc + 0][lrow] = a0.x; As[kc + 1][lrow] = a0.y;
            As[kc + 2][lrow] = a0.z; As[kc + 3][lrow] = a0.w;
            As[kc + 4][lrow] = a1.x; As[kc + 5][lrow] = a1.y;
            As[kc + 6][lrow] = a1.z; As[kc + 7][lrow] = a1.w;
            Bs[kc + 0][lrow] = b0.x; Bs[kc + 1][lrow] = b0.y;
            Bs[kc + 2][lrow] = b0.z; Bs[kc + 3][lrow] = b0.w;
            Bs[kc + 4][lrow] = b1.x; Bs[kc + 5][lrow] = b1.y;
            Bs[kc + 6][lrow] = b1.z; Bs[kc + 7][lrow] = b1.w;
            __syncthreads();
#pragma unroll
            for (int k = 0; k < KCP; ++k) {
                f32x4 av = *(const f32x4*)&As[k][4 * ty];
                f32x4 bv = *(const f32x4*)&Bs[k][4 * tx];
#pragma unroll
                for (int a = 0; a < 4; ++a)
#pragma unroll
                    for (int b = 0; b < 4; ++b)
                        acc[a][b] += av[a] * bv[b];
            }
        }

        float lsum = 0.f, lcnt = 0.f;
        int ib = i0 + 4 * ty, jb = j0 + 4 * tx;
#pragma unroll
        for (int a = 0; a < 4; ++a)
#pragma unroll
            for (int b = 0; b < 4; ++b) {
                int i = ib + a, j = jb + b;
                if (j > i && j < CC) {
                    float d2 = sqw[i] + sqw[j] - 2.f * acc[a][b];
                    if (d2 > 0.f) { lsum += 1.f / d2; lcnt += 1.f; }
                }
            }
        lsum = wave_reduce(lsum);
        lcnt = wave_reduce(lcnt);
        int wv = t >> 6;
        if ((t & 63) == 0) { rs[wv] = lsum; rc[wv] = lcnt; }
        __syncthreads();
        if (t == 0) {
            atomicAdd(pair_acc + 0, rs[0] + rs[1] + rs[2] + rs[3]);
            atomicAdd(pair_acc + 1, rc[0] + rc[1] + rc[2] + rc[3]);
        }
        return;
    }

    // ---------------- sample term: one wave per 2 rows, no LDS, no barriers ----
    int lane = t & 63;
    long long gw = (long long)(blockIdx.x - NPAIR) * 4 + (t >> 6);
    long long r0 = gw * 2;  // rows r0, r0+1

    const f32x4* f4 = (const f32x4*)feat;
    const f32x4* w4 = (const f32x4*)w;

    int tg0 = target[r0];
    int tg1 = target[r0 + 1];

    size_t fb = (size_t)r0 * 128 + lane;
    f32x4 a0 = __builtin_nontemporal_load(f4 + fb);
    f32x4 a1 = __builtin_nontemporal_load(f4 + fb + 64);
    f32x4 b0 = __builtin_nontemporal_load(f4 + fb + 128);
    f32x4 b1 = __builtin_nontemporal_load(f4 + fb + 192);

    f32x4 u0 = w4[(size_t)tg0 * 128 + lane];
    f32x4 u1 = w4[(size_t)tg0 * 128 + 64 + lane];
    f32x4 v0 = w4[(size_t)tg1 * 128 + lane];
    f32x4 v1 = w4[(size_t)tg1 * 128 + 64 + lane];

    float* orow0 = out_feat + (size_t)r0 * 512;
    store_row(orow0, lane, a0, a1);
    store_row(orow0 + 512, lane, b0, b1);

    float ff0 = dot4(a0, a0) + dot4(a1, a1);
    float fw0 = dot4(a0, u0) + dot4(a1, u1);
    float ff1 = dot4(b0, b0) + dot4(b1, b1);
    float fw1 = dot4(b0, v0) + dot4(b1, v1);

#pragma unroll
    for (int m = 32; m > 0; m >>= 1) {
        ff0 += __shfl_xor(ff0, m, 64);
        fw0 += __shfl_xor(fw0, m, 64);
        ff1 += __shfl_xor(ff1, m, 64);
        fw1 += __shfl_xor(fw1, m, 64);
    }

    if (lane == 0) {
        float inv = rsqrtf(ff0);
        float d2 = ff0 * inv * inv + sqw[tg0] - 2.f * inv * fw0;
        d2 = fmaxf(d2, 0.f);
        atomicAdd(class_sum + tg0, sqrtf(d2));
        atomicAdd(class_cnt + tg0, 1.f);
    } else if (lane == 1) {
        float inv = rsqrtf(ff1);
        float d2 = ff1 * inv * inv + sqw[tg1] - 2.f * inv * fw1;
        d2 = fmaxf(d2, 0.f);
        atomicAdd(class_sum + tg1, sqrtf(d2));
        atomicAdd(class_cnt + tg1, 1.f);
    }
}

// --- finalize both scalars ---
__global__ __launch_bounds__(256) void kfin(const float* __restrict__ class_sum,
                                            const float* __restrict__ class_cnt,
                                            const float* __restrict__ pair_acc,
                                            float* __restrict__ out) {
    float msum = 0.f, pcnt = 0.f;
    for (int c = threadIdx.x; c < CC; c += 256) {
        float cnt = class_cnt[c];
        if (cnt > 0.f) {
            msum += class_sum[c] / cnt;
            pcnt += 1.f;
        }
    }
    msum = wave_reduce(msum);
    pcnt = wave_reduce(pcnt);
    __shared__ float rs[4], rc[4];
    int wv = threadIdx.x >> 6;
    if ((threadIdx.x & 63) == 0) { rs[wv] = msum; rc[wv] = pcnt; }
    __syncthreads();
    if (threadIdx.x == 0) {
        float sm = rs[0] + rs[1] + rs[2] + rs[3];
        float sp = rc[0] + rc[1] + rc[2] + rc[3];
        out[0] = 1.0f * (sm / sp);                   // BETA * sample_wise
        out[1] = 1.0f * (pair_acc[0] / pair_acc[1]); // ALPHA * weight_wise
    }
}

extern "C" void kernel_launch(void* const* d_in, const int* in_sizes, int n_in,
                              void* d_out, int out_size, void* d_ws, size_t ws_size,
                              hipStream_t stream) {
    const float* feat = (const float*)d_in[0];
    const float* cls = (const float*)d_in[1];
    const int* target = (const int*)d_in[2];
    float* out = (float*)d_out;
    float* ws = (float*)d_ws;

    float* w = ws;
    float* sqw = ws + 512000;
    float* class_sum = ws + 513000;
    float* class_cnt = ws + 514000;
    float* pair_acc = ws + 515000;

    // zero accumulators (class_sum, class_cnt, pair_acc are contiguous)
    hipMemsetAsync(class_sum, 0, (2 * CC + 2) * sizeof(float), stream);

    knorm<<<CC, 64, 0, stream>>>(cls, w, sqw);
    kmain<<<NPAIR + NSAMP, 256, 0, stream>>>(feat, target, w, sqw,
                                             class_sum, class_cnt, pair_acc, out + 2);
    kfin<<<1, 256, 0, stream>>>(class_sum, class_cnt, pair_acc, out);
}